// Round 5
// baseline (506.527 us; speedup 1.0000x reference)
//
#include <hip/hip_runtime.h>
#include <cstdint>

#define T_SEQ 40
#define NB    16384
#define NH    128
#define NROWS 136          // 128 recurrent rows + 8 input rows
#define ROWD  129          // staging writes lane-stride 129 -> bank-stride 1; reads lane-stride 1: conflict-free
#define WPB   16           // waves per block
#define NTHR  (WPB * 64)
#define NBLK  512          // persistent: 2 blocks/CU co-resident; each wave owns 2 batch rows

typedef float v2f __attribute__((ext_vector_type(2)));   // -> v_pk_*_f32

// ---- wave-wide sum of two floats via DPP (VALU pipe; keeps DS pipe free) ----
template <int C>
__device__ __forceinline__ float dppstep(float v) {
  int t = __builtin_amdgcn_update_dpp(0, __float_as_int(v), C, 0xF, 0xF, true);
  return v + __int_as_float(t);
}
__device__ __forceinline__ void wave_sum2(float &a, float &b) {
  a = dppstep<0x111>(a); b = dppstep<0x111>(b);   // row_shr:1
  a = dppstep<0x112>(a); b = dppstep<0x112>(b);   // row_shr:2
  a = dppstep<0x114>(a); b = dppstep<0x114>(b);   // row_shr:4
  a = dppstep<0x118>(a); b = dppstep<0x118>(b);   // row_shr:8
  a = dppstep<0x142>(a); b = dppstep<0x142>(b);   // row_bcast15
  a = dppstep<0x143>(a); b = dppstep<0x143>(b);   // row_bcast31 -> lane63 total
  a = __int_as_float(__builtin_amdgcn_readlane(__float_as_int(a), 63));
  b = __int_as_float(__builtin_amdgcn_readlane(__float_as_int(b), 63));
}

__global__ __launch_bounds__(NTHR, 8)
void Policy_22033182228693_kernel(const float* __restrict__ x,
                                  const float* __restrict__ w_in,
                                  const float* __restrict__ w_rec,
                                  const float* __restrict__ w_out,
                                  const float* __restrict__ dmask,
                                  float* __restrict__ out)
{
  __shared__ float W[NROWS * ROWD];   // 70,176 B -> 2 blocks/CU = 32 waves

  const int tid = threadIdx.x;
  for (int e = tid; e < NH * NH; e += NTHR) {        // W[j][h] = w_rec[h][j]
    int h = e >> 7, j = e & 127;
    W[j * ROWD + h] = w_rec[e];
  }
  for (int e = tid; e < NH * 8; e += NTHR) {         // W[128+k][h] = w_in[h][k]
    int h = e >> 3, k = e & 7;
    W[(128 + k) * ROWD + h] = w_in[e];
  }
  __syncthreads();   // only barrier

  const int wave = tid >> 6;
  const int lane = tid & 63;   // lane owns neurons h=lane, h=lane+64
  const int gw   = blockIdx.x * WPB + wave;   // global wave id: 0..8191; owns rows 2*gw, 2*gw+1

  // Row-independent readout weights (w_out shape (2,128))
  const float wo00 = w_out[lane];
  const float wo01 = w_out[lane + 64];
  const float wo10 = w_out[128 + lane];
  const float wo11 = w_out[192 + lane];

  const size_t TS = (size_t)NB * NH;          // dwords per timestep in dmask

#pragma unroll 1
  for (int rr = 0; rr < 2; ++rr) {
    const int b = gw * 2 + rr;

    // ---- per-row prologue ----
    float xv = x[(size_t)b * 4 + (lane & 3)];
    float cc = fmaxf(0.f, ((lane & 4) ? -50.f : 50.f) * xv);
    if (lane >= 8) cc = 0.f;

    // Channels with cc > 10 spike EVERY step; fold their w_in rows into a constant.
    bool always = cc > 10.f;
    uint64_t aM = __ballot((int)always);
    if (always) cc = 0.f;
    v2f cin; cin.x = 0.f; cin.y = 0.f;
    for (uint64_t m = aM; m; m &= m - 1) {
      int o = (128 + __builtin_ctzll(m)) * ROWD;
      cin.x += W[o + lane];
      cin.y += W[o + lane + 64];
    }

    const float* gmu = dmask + (size_t)b * NH;  // wave-uniform base
    float mc0 = gmu[lane],      mc1 = gmu[lane + 64];
    float mn0 = gmu[TS + lane], mn1 = gmu[TS + lane + 64];

    float ve = 0.f;
    v2f v;  v.x = 0.f;  v.y = 0.f;
    v2f i;  i.x = 0.f;  i.y = 0.f;
    float io0 = 0.f, io1 = 0.f, vo0 = 0.f, vo1 = 0.f;
    float m0 = -3.0e38f, m1 = -3.0e38f;
    uint64_t bE = 0, bO = 0;

#pragma unroll 1
    for (int t = 0; t < T_SEQ; ++t) {
      // encoder (slow channels only)
      ve += 0.1f * (cc - ve);
      bool zi = ve > 1.0f;
      if (zi) ve = 0.f;
      uint64_t bI = __ballot((int)zi);

      // hidden membrane (uses old i) — packed
      v2f vd = v + 0.1f * (i - v);
      bool z0 = vd.x > 1.0f, z1 = vd.y > 1.0f;
      v.x = z0 ? 0.f : vd.x;
      v.y = z1 ? 0.f : vd.y;

      // synaptic current: decay + sparse gather (prev z), fused dual-mask, packed adds
      v2f a = 0.8f * i;
      {
        uint64_t mA = bE, mB = bO;
        int nA = __popcll(mA), nB = __popcll(mB);
        int nP = nA < nB ? nA : nB;
        if (nP > 0) {
          int oA = __builtin_ctzll(mA) * ROWD;        mA &= mA - 1;
          int oB = (64 + __builtin_ctzll(mB)) * ROWD; mB &= mB - 1;
          v2f p; p.x = W[oA + lane]; p.y = W[oA + lane + 64];
          v2f q; q.x = W[oB + lane]; q.y = W[oB + lane + 64];
#pragma unroll 2
          for (int k = 1; k < nP; ++k) {
            int o2 = __builtin_ctzll(mA) * ROWD;        mA &= mA - 1;
            int o3 = (64 + __builtin_ctzll(mB)) * ROWD; mB &= mB - 1;
            v2f r; r.x = W[o2 + lane]; r.y = W[o2 + lane + 64];
            v2f s; s.x = W[o3 + lane]; s.y = W[o3 + lane + 64];
            a += p + q;
            p = r; q = s;
          }
          a += p + q;
        }
        // drain: at most one of mA/mB nonzero
        uint64_t mR; int rb;
        if (mA) { mR = mA; rb = 0; } else { mR = mB; rb = 64; }
        while (mR) {
          int o = (rb + __builtin_ctzll(mR)) * ROWD; mR &= mR - 1;
          v2f w; w.x = W[o + lane]; w.y = W[o + lane + 64];
          a += w;
        }
        // slow input channels (rare)
        while (bI) {
          int o = (128 + __builtin_ctzll(bI)) * ROWD; bI &= bI - 1;
          v2f w; w.x = W[o + lane]; w.y = W[o + lane + 64];
          a += w;
        }
        a += cin;    // always-on input contribution
      }
      i = a;

      bE = __ballot((int)z0);
      bO = __ballot((int)z1);

      // dropout + readout
      float mt0 = mc0, mt1 = mc1;
      mc0 = mn0; mc1 = mn1;
      int tp = (t + 2 < T_SEQ) ? t + 2 : T_SEQ - 1;
      size_t so = (size_t)tp * TS;
      mn0 = gmu[so + lane];
      mn1 = gmu[so + lane + 64];

      float zd0 = z0 ? mt0 : 0.f;
      float zd1 = z1 ? mt1 : 0.f;
      float u0 = zd0 * wo00 + zd1 * wo01;
      float u1 = zd0 * wo10 + zd1 * wo11;
      if (bE | bO) {
        wave_sum2(u0, u1);
      } else {
        u0 = 0.f; u1 = 0.f;
      }

      vo0 += 0.1f * (io0 - vo0);
      vo1 += 0.1f * (io1 - vo1);
      io0 = 0.8f * io0 + u0;
      io1 = 0.8f * io1 + u1;
      m0 = fmaxf(m0, vo0);
      m1 = fmaxf(m1, vo1);
    }

    if (lane == 0) {
      float mx = fmaxf(m0, m1);
      float e0 = expf(m0 - mx), e1 = expf(m1 - mx);
      float inv = 1.f / (e0 + e1);
      ((float2*)out)[b] = make_float2(e0 * inv, e1 * inv);
    }
  }
}

extern "C" void kernel_launch(void* const* d_in, const int* in_sizes, int n_in,
                              void* d_out, int out_size, void* d_ws, size_t ws_size,
                              hipStream_t stream) {
  const float* x     = (const float*)d_in[0];
  const float* w_in  = (const float*)d_in[1];
  const float* w_rec = (const float*)d_in[2];
  const float* w_out = (const float*)d_in[3];
  const float* dmask = (const float*)d_in[4];
  float* out = (float*)d_out;

  hipLaunchKernelGGL(Policy_22033182228693_kernel, dim3(NBLK), dim3(NTHR), 0, stream,
                     x, w_in, w_rec, w_out, dmask, out);
}